// Round 1
// baseline (271.382 us; speedup 1.0000x reference)
//
#include <hip/hip_runtime.h>

#define B_ 4096
#define T_ 256
#define I_ 16
#define H_ 32

// fast sigmoid / tanh via v_exp_f32 + v_rcp_f32 (plenty accurate vs 7.5e-3 abs tol)
__device__ __forceinline__ float sigm_(float x) {
    float e = __expf(-x);
    return __builtin_amdgcn_rcpf(1.0f + e);
}
__device__ __forceinline__ float tanh_(float x) {
    float e = __expf(-2.0f * x);
    float r = __builtin_amdgcn_rcpf(1.0f + e);
    return __fmaf_rn(2.0f, r, -1.0f);
}

// One 64-thread block = 1 wave = 2 batch elements (32 lanes each).
// Lane j of a 32-lane group owns h_j, c_j and computes gate rows {j, 32+j, 64+j, 96+j}.
// Weights held in VGPRs (192 floats/lane). h broadcast via LDS (2-way = conflict-free).
__global__ __launch_bounds__(64, 2)
void lstm_fused_kernel(const float* __restrict__ x,
                       const float* __restrict__ Wih,
                       const float* __restrict__ Whh,
                       const float* __restrict__ bih,
                       const float* __restrict__ bhh,
                       const float* __restrict__ Wfc,
                       const float* __restrict__ bfc,
                       float* __restrict__ out)
{
    __shared__ __align__(16) float hbuf[2][H_];
    __shared__ __align__(16) float xbuf[2][8 * I_];

    const int tid  = threadIdx.x;
    const int elem = tid >> 5;   // 0 or 1
    const int idx  = tid & 31;   // hidden-unit index this lane owns
    const int b    = blockIdx.x * 2 + elem;

    // ---- load per-lane weight rows into registers ----
    float wih[4][I_];
    float whh[4][H_];
    float bias[4];
#pragma unroll
    for (int q = 0; q < 4; ++q) {
        const int row = q * 32 + idx;   // PyTorch gate order: i,f,g,o
#pragma unroll
        for (int k4 = 0; k4 < I_ / 4; ++k4) {
            const float4 v = *reinterpret_cast<const float4*>(Wih + row * I_ + k4 * 4);
            wih[q][k4 * 4 + 0] = v.x; wih[q][k4 * 4 + 1] = v.y;
            wih[q][k4 * 4 + 2] = v.z; wih[q][k4 * 4 + 3] = v.w;
        }
#pragma unroll
        for (int j4 = 0; j4 < H_ / 4; ++j4) {
            const float4 v = *reinterpret_cast<const float4*>(Whh + row * H_ + j4 * 4);
            whh[q][j4 * 4 + 0] = v.x; whh[q][j4 * 4 + 1] = v.y;
            whh[q][j4 * 4 + 2] = v.z; whh[q][j4 * 4 + 3] = v.w;
        }
        bias[q] = bih[row] + bhh[row];
    }

    hbuf[elem][idx] = 0.0f;
    float c  = 0.0f;
    float hj = 0.0f;
    __syncthreads();

    const float* xb = x + (size_t)b * (T_ * I_);
    // prefetch first 8-timestep x block (128 floats per element, 1 float4/lane)
    float4 xnext = *reinterpret_cast<const float4*>(xb + idx * 4);

    for (int tb = 0; tb < T_ / 8; ++tb) {
        // stage prefetched x block; issue next prefetch early (hides ~8 timesteps)
        *reinterpret_cast<float4*>(&xbuf[elem][idx * 4]) = xnext;
        if (tb + 1 < T_ / 8) {
            xnext = *reinterpret_cast<const float4*>(xb + (tb + 1) * (8 * I_) + idx * 4);
        }
        __syncthreads();

#pragma unroll
        for (int tt = 0; tt < 8; ++tt) {
            float ai = bias[0], af = bias[1], ag = bias[2], ao = bias[3];

            // x contribution: dot16 per gate (broadcast LDS reads)
            const float* xt = &xbuf[elem][tt * I_];
#pragma unroll
            for (int k4 = 0; k4 < I_ / 4; ++k4) {
                const float4 xv = *reinterpret_cast<const float4*>(xt + k4 * 4);
                const float xs0 = xv.x, xs1 = xv.y, xs2 = xv.z, xs3 = xv.w;
                ai = __fmaf_rn(xs0, wih[0][k4 * 4 + 0], ai);
                af = __fmaf_rn(xs0, wih[1][k4 * 4 + 0], af);
                ag = __fmaf_rn(xs0, wih[2][k4 * 4 + 0], ag);
                ao = __fmaf_rn(xs0, wih[3][k4 * 4 + 0], ao);
                ai = __fmaf_rn(xs1, wih[0][k4 * 4 + 1], ai);
                af = __fmaf_rn(xs1, wih[1][k4 * 4 + 1], af);
                ag = __fmaf_rn(xs1, wih[2][k4 * 4 + 1], ag);
                ao = __fmaf_rn(xs1, wih[3][k4 * 4 + 1], ao);
                ai = __fmaf_rn(xs2, wih[0][k4 * 4 + 2], ai);
                af = __fmaf_rn(xs2, wih[1][k4 * 4 + 2], af);
                ag = __fmaf_rn(xs2, wih[2][k4 * 4 + 2], ag);
                ao = __fmaf_rn(xs2, wih[3][k4 * 4 + 2], ao);
                ai = __fmaf_rn(xs3, wih[0][k4 * 4 + 3], ai);
                af = __fmaf_rn(xs3, wih[1][k4 * 4 + 3], af);
                ag = __fmaf_rn(xs3, wih[2][k4 * 4 + 3], ag);
                ao = __fmaf_rn(xs3, wih[3][k4 * 4 + 3], ao);
            }

            // h contribution: dot32 per gate (broadcast LDS reads of h)
#pragma unroll
            for (int j4 = 0; j4 < H_ / 4; ++j4) {
                const float4 hv = *reinterpret_cast<const float4*>(&hbuf[elem][j4 * 4]);
                const float h0 = hv.x, h1 = hv.y, h2 = hv.z, h3 = hv.w;
                ai = __fmaf_rn(h0, whh[0][j4 * 4 + 0], ai);
                af = __fmaf_rn(h0, whh[1][j4 * 4 + 0], af);
                ag = __fmaf_rn(h0, whh[2][j4 * 4 + 0], ag);
                ao = __fmaf_rn(h0, whh[3][j4 * 4 + 0], ao);
                ai = __fmaf_rn(h1, whh[0][j4 * 4 + 1], ai);
                af = __fmaf_rn(h1, whh[1][j4 * 4 + 1], af);
                ag = __fmaf_rn(h1, whh[2][j4 * 4 + 1], ag);
                ao = __fmaf_rn(h1, whh[3][j4 * 4 + 1], ao);
                ai = __fmaf_rn(h2, whh[0][j4 * 4 + 2], ai);
                af = __fmaf_rn(h2, whh[1][j4 * 4 + 2], af);
                ag = __fmaf_rn(h2, whh[2][j4 * 4 + 2], ag);
                ao = __fmaf_rn(h2, whh[3][j4 * 4 + 2], ao);
                ai = __fmaf_rn(h3, whh[0][j4 * 4 + 3], ai);
                af = __fmaf_rn(h3, whh[1][j4 * 4 + 3], af);
                ag = __fmaf_rn(h3, whh[2][j4 * 4 + 3], ag);
                ao = __fmaf_rn(h3, whh[3][j4 * 4 + 3], ao);
            }

            const float gi = sigm_(ai);
            const float gf = sigm_(af);
            const float gg = tanh_(ag);
            const float go = sigm_(ao);

            c  = __fmaf_rn(gf, c, gi * gg);
            hj = go * tanh_(c);

            hbuf[elem][idx] = hj;     // lockstep wave: all reads above already issued
            __syncthreads();          // 1-wave block -> lowers to lgkmcnt wait
        }
    }

    // ---- epilogue: out[b] = h_last . W_fc + b_fc ----
    float p = hj * Wfc[idx];
#pragma unroll
    for (int off = 16; off > 0; off >>= 1) {
        p += __shfl_down(p, off, 32);
    }
    if (idx == 0) {
        out[b] = p + bfc[0];
    }
}

extern "C" void kernel_launch(void* const* d_in, const int* in_sizes, int n_in,
                              void* d_out, int out_size, void* d_ws, size_t ws_size,
                              hipStream_t stream) {
    const float* x   = (const float*)d_in[0];
    const float* Wih = (const float*)d_in[1];
    const float* Whh = (const float*)d_in[2];
    const float* bih = (const float*)d_in[3];
    const float* bhh = (const float*)d_in[4];
    const float* Wfc = (const float*)d_in[5];
    const float* bfc = (const float*)d_in[6];
    float* out = (float*)d_out;

    dim3 grid(B_ / 2);
    dim3 block(64);
    hipLaunchKernelGGL(lstm_fused_kernel, grid, block, 0, stream,
                       x, Wih, Whh, bih, bhh, Wfc, bfc, out);
}

// Round 3
// 239.563 us; speedup vs baseline: 1.1328x; 1.1328x over previous
//
#include <hip/hip_runtime.h>

#define B_ 4096
#define T_ 256
#define I_ 16
#define H_ 32

typedef _Float16 half2_t __attribute__((ext_vector_type(2)));
typedef _Float16 half4_t __attribute__((ext_vector_type(4)));
typedef _Float16 half8_t __attribute__((ext_vector_type(8)));

union H8 {
    half8_t v;
    half2_t h[4];
};

// sigmoid / tanh via v_exp_f32 (2^x) + v_rcp_f32
__device__ __forceinline__ float sigm_(float x) {
    float e = __builtin_amdgcn_exp2f(-1.442695041f * x);
    return __builtin_amdgcn_rcpf(1.0f + e);
}
__device__ __forceinline__ float tanh_(float x) {
    float e = __builtin_amdgcn_exp2f(-2.885390082f * x);
    float r = __builtin_amdgcn_rcpf(1.0f + e);
    return __fmaf_rn(2.0f, r, -1.0f);
}

// One 64-thread block = 1 wave = 2 batch elements (32 lanes each).
// Lane j owns h_j, c_j and computes gate rows {j, 32+j, 64+j, 96+j} via f16 dot2.
// Weights packed f16x2 in VGPRs (96 regs). h/x exchanged via LDS as f16.
__global__ __launch_bounds__(64, 4)
void lstm_fused_f16(const float* __restrict__ x,
                    const float* __restrict__ Wih,
                    const float* __restrict__ Whh,
                    const float* __restrict__ bih,
                    const float* __restrict__ bhh,
                    const float* __restrict__ Wfc,
                    const float* __restrict__ bfc,
                    float* __restrict__ out)
{
    __shared__ __align__(16) _Float16 hbuf[2][H_];        // 128 B
    __shared__ __align__(16) _Float16 xbuf[2][8 * I_];    // 512 B

    const int tid  = threadIdx.x;
    const int elem = tid >> 5;
    const int idx  = tid & 31;
    const int b    = blockIdx.x * 2 + elem;

    // ---- load + f16-pack per-lane weight rows ----
    half2_t wih2[4][I_ / 2];   // 32 VGPR
    half2_t whh2[4][H_ / 2];   // 64 VGPR
    float bias[4];
#pragma unroll
    for (int q = 0; q < 4; ++q) {
        const int row = q * 32 + idx;   // gate order i,f,g,o
        const float4* pih = reinterpret_cast<const float4*>(Wih + row * I_);
#pragma unroll
        for (int k = 0; k < I_ / 4; ++k) {
            const float4 v = pih[k];
            wih2[q][2 * k + 0] = half2_t{(_Float16)v.x, (_Float16)v.y};
            wih2[q][2 * k + 1] = half2_t{(_Float16)v.z, (_Float16)v.w};
        }
        const float4* phh = reinterpret_cast<const float4*>(Whh + row * H_);
#pragma unroll
        for (int k = 0; k < H_ / 4; ++k) {
            const float4 v = phh[k];
            whh2[q][2 * k + 0] = half2_t{(_Float16)v.x, (_Float16)v.y};
            whh2[q][2 * k + 1] = half2_t{(_Float16)v.z, (_Float16)v.w};
        }
        bias[q] = bih[row] + bhh[row];
    }

    hbuf[elem][idx] = (_Float16)0.0f;
    float c  = 0.0f;
    float hj = 0.0f;
    __syncthreads();

    const float* xb = x + (size_t)b * (T_ * I_);
    float4 xnext = *reinterpret_cast<const float4*>(xb + idx * 4);

    for (int tb = 0; tb < T_ / 8; ++tb) {
        // stage prefetched x block as f16 (one ds_write_b64/lane)
        half4_t xs;
        xs[0] = (_Float16)xnext.x; xs[1] = (_Float16)xnext.y;
        xs[2] = (_Float16)xnext.z; xs[3] = (_Float16)xnext.w;
        *reinterpret_cast<half4_t*>(&xbuf[elem][idx * 4]) = xs;
        if (tb + 1 < T_ / 8) {
            xnext = *reinterpret_cast<const float4*>(xb + (tb + 1) * (8 * I_) + idx * 4);
        }
        __syncthreads();

#pragma unroll
        for (int tt = 0; tt < 8; ++tt) {
            float ai = bias[0], af = bias[1], ag = bias[2], ao = bias[3];

            // x contribution: 16 dims = 8 half2 (2x ds_read_b128, broadcast)
            H8 xv0, xv1;
            xv0.v = *reinterpret_cast<const half8_t*>(&xbuf[elem][tt * I_]);
            xv1.v = *reinterpret_cast<const half8_t*>(&xbuf[elem][tt * I_ + 8]);
#pragma unroll
            for (int k = 0; k < 4; ++k) {
                ai = __builtin_amdgcn_fdot2(xv0.h[k], wih2[0][k], ai, false);
                af = __builtin_amdgcn_fdot2(xv0.h[k], wih2[1][k], af, false);
                ag = __builtin_amdgcn_fdot2(xv0.h[k], wih2[2][k], ag, false);
                ao = __builtin_amdgcn_fdot2(xv0.h[k], wih2[3][k], ao, false);
            }
#pragma unroll
            for (int k = 0; k < 4; ++k) {
                ai = __builtin_amdgcn_fdot2(xv1.h[k], wih2[0][4 + k], ai, false);
                af = __builtin_amdgcn_fdot2(xv1.h[k], wih2[1][4 + k], af, false);
                ag = __builtin_amdgcn_fdot2(xv1.h[k], wih2[2][4 + k], ag, false);
                ao = __builtin_amdgcn_fdot2(xv1.h[k], wih2[3][4 + k], ao, false);
            }

            // h contribution: 32 dims = 16 half2 (4x ds_read_b128, broadcast)
#pragma unroll
            for (int j8 = 0; j8 < 4; ++j8) {
                H8 hv;
                hv.v = *reinterpret_cast<const half8_t*>(&hbuf[elem][j8 * 8]);
#pragma unroll
                for (int k = 0; k < 4; ++k) {
                    const int p = j8 * 4 + k;
                    ai = __builtin_amdgcn_fdot2(hv.h[k], whh2[0][p], ai, false);
                    af = __builtin_amdgcn_fdot2(hv.h[k], whh2[1][p], af, false);
                    ag = __builtin_amdgcn_fdot2(hv.h[k], whh2[2][p], ag, false);
                    ao = __builtin_amdgcn_fdot2(hv.h[k], whh2[3][p], ao, false);
                }
            }

            const float gi = sigm_(ai);
            const float gf = sigm_(af);
            const float gg = tanh_(ag);
            const float go = sigm_(ao);

            c  = __fmaf_rn(gf, c, gi * gg);
            hj = go * tanh_(c);

            hbuf[elem][idx] = (_Float16)hj;   // lockstep wave: reads above already issued
            __syncthreads();
        }
    }

    // ---- epilogue: out[b] = h_last . W_fc + b_fc ----
    float p = hj * Wfc[idx];
#pragma unroll
    for (int off = 16; off > 0; off >>= 1) {
        p += __shfl_down(p, off, 32);
    }
    if (idx == 0) {
        out[b] = p + bfc[0];
    }
}

extern "C" void kernel_launch(void* const* d_in, const int* in_sizes, int n_in,
                              void* d_out, int out_size, void* d_ws, size_t ws_size,
                              hipStream_t stream) {
    const float* x   = (const float*)d_in[0];
    const float* Wih = (const float*)d_in[1];
    const float* Whh = (const float*)d_in[2];
    const float* bih = (const float*)d_in[3];
    const float* bhh = (const float*)d_in[4];
    const float* Wfc = (const float*)d_in[5];
    const float* bfc = (const float*)d_in[6];
    float* out = (float*)d_out;

    dim3 grid(B_ / 2);
    dim3 block(64);
    hipLaunchKernelGGL(lstm_fused_f16, grid, block, 0, stream,
                       x, Wih, Whh, bih, bhh, Wfc, bfc, out);
}